// Round 6
// baseline (753.773 us; speedup 1.0000x reference)
//
// MOC_Branch_KwithM on MI355X (gfx950).
// Pipeline: [proj GEMM -> Q/K/V f16] -> [flash attn: 1-wave blocks, QBLK=32,
//   direct-L2 K/V fragment reads, key-split x4 + combine] -> [Wz GEMM + BN +
//   residual] -> [shrink GEMM + BN -> padded f16 S] -> [3x3 convs as f16 MFMA
//   implicit GEMM] -> [1x1 heads].
#include <hip/hip_runtime.h>
#include <cstddef>

#define DI __device__ __forceinline__

typedef float    f32x4 __attribute__((ext_vector_type(4)));
typedef float    f32x2 __attribute__((ext_vector_type(2)));
typedef _Float16 half8 __attribute__((ext_vector_type(8)));

namespace {

constexpr int KF = 7;
constexpr int C  = 256;
constexpr int HW = 1296;     // 36*36
constexpr int NN = 9072;     // KF*HW
constexpr int NP = 9088;     // NN padded to multiple of 64
constexpr int IC = 128;
constexpr int PR = 38;       // padded spatial row
constexpr int PADP = PR * PR;  // 1444

DI f32x4 mfma16(half8 a, half8 b, f32x4 c) {
  return __builtin_amdgcn_mfma_f32_16x16x32_f16(a, b, c, 0, 0, 0);
}

DI unsigned pk2h(float a, float b) {
  unsigned short ua = __builtin_bit_cast(unsigned short, (_Float16)a);
  unsigned short ub = __builtin_bit_cast(unsigned short, (_Float16)b);
  return (unsigned)ua | ((unsigned)ub << 16);
}

// ---------------- generic tiled fp32 GEMM:  C[M,N] = A[M,K] @ B[K,N] ----------------
template<int K, int BN, class Op>
__global__ __launch_bounds__(256) void gemm_t(Op op) {
  constexpr int MN = BN / 16;
  __shared__ float As[16][64];
  __shared__ float Bs[16][BN];
  const int b  = blockIdx.z;
  const int m0 = blockIdx.y * 64;
  const int n0 = blockIdx.x * BN;
  const int tid = threadIdx.x;
  const int tx = tid & 15, ty = tid >> 4;
  float acc[4][MN] = {};
  for (int k0 = 0; k0 < K; k0 += 16) {
    {
      const int am = tid >> 2, ak = (tid & 3) * 4;
      #pragma unroll
      for (int i = 0; i < 4; i++) As[ak + i][am] = op.lda(b, m0 + am, k0 + ak + i);
    }
    {
      const int nn = tid % BN;
      const int kb = tid / BN;
      #pragma unroll
      for (int r = 0; r < (16 * BN) / 256; r++) {
        const int kk = kb + r * (256 / BN);
        Bs[kk][nn] = op.ldb(b, k0 + kk, n0 + nn);
      }
    }
    __syncthreads();
    #pragma unroll
    for (int kk = 0; kk < 16; kk++) {
      const f32x4 a = *(const f32x4*)&As[kk][ty * 4];
      f32x4 bv[MN / 4];
      #pragma unroll
      for (int j4 = 0; j4 < MN / 4; j4++) bv[j4] = *(const f32x4*)&Bs[kk][tx * MN + j4 * 4];
      #pragma unroll
      for (int i = 0; i < 4; i++)
        #pragma unroll
        for (int j = 0; j < MN; j++)
          acc[i][j] = fmaf(a[i], bv[j / 4][j & 3], acc[i][j]);
    }
    __syncthreads();
  }
  #pragma unroll
  for (int i = 0; i < 4; i++)
    #pragma unroll
    for (int j = 0; j < MN; j++)
      op.st(b, m0 + ty * 4 + i, n0 + tx * MN + j, acc[i][j]);
}

// proj: rows 0-127 = theta -> Q(n,128), 128-255 = phi -> Kb(n,128), 256-383 = g -> Vt(128,n)
struct ProjOp {
  const float *thw, *phw, *gw, *thb, *phb, *gb, *x;
  _Float16 *Q, *Kb, *Vt;
  DI float lda(int b, int m, int k) const {
    const int sel = m >> 7, r = m & 127;
    const float* w = sel == 0 ? thw : (sel == 1 ? phw : gw);
    return w[r * 256 + k];
  }
  DI float ldb(int b, int k, int n) const {
    if (n >= NN) return 0.f;
    const int fr = n / HW, hw = n % HW;
    return x[((b * KF + fr) * C + k) * HW + hw];
  }
  DI void st(int b, int m, int n, float v) const {
    if (n >= NN) return;
    const int sel = m >> 7, r = m & 127;
    const float* bias = sel == 0 ? thb : (sel == 1 ? phb : gb);
    const _Float16 h = (_Float16)(v + bias[r]);
    if (sel == 0)      Q [(size_t)(b * NP + n) * IC + r] = h;
    else if (sel == 1) Kb[(size_t)(b * NP + n) * IC + r] = h;
    else               Vt[(size_t)(b * IC + r) * NP + n] = h;
  }
};

// Wz @ y + bias -> BN -> + xn residual -> Z (b,256,NN)
struct WzOp {
  const float *w, *bias, *g, *be, *mu, *var, *x, *Y;
  float* Z;
  DI float lda(int b, int m, int k) const { return w[m * IC + k]; }
  DI float ldb(int b, int k, int n) const { return n < NN ? Y[(size_t)(b * IC + k) * NN + n] : 0.f; }
  DI void st(int b, int m, int n, float v) const {
    if (n >= NN) return;
    const float s = g[m] / sqrtf(var[m] + 1e-5f);
    float val = (v + bias[m] - mu[m]) * s + be[m];
    const int fr = n / HW, hw = n % HW;
    val += x[((b * KF + fr) * C + m) * HW + hw];
    Z[(size_t)(b * C + m) * NN + n] = val;
  }
};

// shrink (64x256) @ Z -> BN -> padded f16 S [14][PADP][64]
struct ShOp {
  const float *w, *g, *be, *mu, *var, *Z;
  _Float16* Sp;
  DI float lda(int b, int m, int k) const { return w[m * C + k]; }
  DI float ldb(int b, int k, int n) const { return n < NN ? Z[(size_t)(b * C + k) * NN + n] : 0.f; }
  DI void st(int b, int m, int n, float v) const {
    if (n >= NN) return;
    const float s = g[m] / sqrtf(var[m] + 1e-5f);
    const float val = (v - mu[m]) * s + be[m];
    const int fr = n / HW, hw = n % HW;
    const int r = hw / 36, c = hw % 36;
    Sp[((size_t)(b * KF + fr) * PADP + (r + 1) * PR + (c + 1)) * 64 + m] = (_Float16)val;
  }
};

// ---------------- flash attention ----------------
// 1 wave per block, 32 q-rows/wave (two 16-row halves sharing every K/V read).
// K/V fragments read DIRECTLY from global: per (split,batch) combo the K+V
// slice is ~1.16 MB and combo = bid&7 pins it to one XCD's L2 (2272 = 8*284).
// No __syncthreads; LDS holds only the P^T repack (4.6 KB). Softmax stats per
// lane via swapped-operand QK^T; partials merged by attn_combine.
__global__ __launch_bounds__(64, 3) void attn_k(const _Float16* __restrict__ Q,
                                                const _Float16* __restrict__ Kb,
                                                const _Float16* __restrict__ Vt,
                                                float* __restrict__ yp,
                                                float* __restrict__ ml) {
  __shared__ _Float16 PL[2][16 * 72];
  const int bid = blockIdx.x;
  const int combo = bid & 7;
  const int split = combo >> 1, b = combo & 1;
  const int qt = bid >> 3;              // 0..283
  const int lane = threadIdx.x;
  const int qc = lane & 15, g = lane >> 4;
  const int q0 = qt * 32;

  half8 qf[2][4];
  #pragma unroll
  for (int h = 0; h < 2; h++) {
    const _Float16* qbase = Q + (size_t)(b * NP + q0 + h * 16 + qc) * IC + g * 8;
    #pragma unroll
    for (int kc = 0; kc < 4; kc++) qf[h][kc] = *(const half8*)(qbase + kc * 32);
  }

  f32x4 ya[2][8];
  #pragma unroll
  for (int h = 0; h < 2; h++)
    #pragma unroll
    for (int o = 0; o < 8; o++) ya[h][o] = 0.f;
  float m[2] = {-1e30f, -1e30f}, l[2] = {0.f, 0.f};

  const int kt0 = split * 35 + (split < 2 ? split : 2);
  const int kt1 = kt0 + 35 + (split < 2 ? 1 : 0);
  const _Float16* kgb = Kb + (size_t)b * NP * IC + (size_t)qc * IC + g * 8;  // + key*IC
  const _Float16* vgb = Vt + (size_t)b * IC * NP + (size_t)qc * NP + g * 8;  // + o16*NP + key

  for (int kt = kt0; kt < kt1; ++kt) {
    const int key0 = kt * 64;
    const int nf = (kt == 141) ? 3 : 4;  // 9072 = 141*64+48 -> 3 valid frags in tail
    f32x4 st[2][4];
    #pragma unroll
    for (int f = 0; f < 4; f++) {
      if (f < nf) {
        const _Float16* kr = kgb + (size_t)(key0 + f * 16) * IC;
        f32x4 a0 = {}; f32x4 a1 = {};
        #pragma unroll
        for (int kc = 0; kc < 4; kc++) {
          const half8 kf = *(const half8*)(kr + kc * 32);   // shared by both q-halves
          a0 = mfma16(kf, qf[0][kc], a0);
          a1 = mfma16(kf, qf[1][kc], a1);
        }
        st[0][f] = a0; st[1][f] = a1;
      } else {
        st[0][f] = -1e30f; st[1][f] = -1e30f;  // masked keys -> exp() = 0
      }
    }
    // online softmax per q-half (stats live in this lane's q-column)
    #pragma unroll
    for (int h = 0; h < 2; h++) {
      float mt = -1e30f;
      #pragma unroll
      for (int f = 0; f < 4; f++)
        #pragma unroll
        for (int r = 0; r < 4; r++) mt = fmaxf(mt, st[h][f][r]);
      mt = fmaxf(mt, __shfl_xor(mt, 16));
      mt = fmaxf(mt, __shfl_xor(mt, 32));
      const float mn = fmaxf(m[h], mt);
      const float sc = __expf(m[h] - mn);
      float ls = 0.f;
      #pragma unroll
      for (int f = 0; f < 4; f++)
        #pragma unroll
        for (int r = 0; r < 4; r++) {
          const float e = __expf(st[h][f][r] - mn);
          st[h][f][r] = e;
          ls += e;
        }
      ls += __shfl_xor(ls, 16);
      ls += __shfl_xor(ls, 32);
      l[h] = l[h] * sc + ls;
      m[h] = mn;
      #pragma unroll
      for (int o = 0; o < 8; o++) ya[h][o] *= sc;
      // pack P^T -> LDS (key = f*16 + g*4 + rp*2 [+1])
      #pragma unroll
      for (int f = 0; f < 4; f++)
        #pragma unroll
        for (int rp = 0; rp < 2; rp++)
          *(unsigned*)&PL[h][qc * 72 + f * 16 + g * 4 + rp * 2] =
              pk2h(st[h][f][rp * 2], st[h][f][rp * 2 + 1]);
    }
    // order pack-writes -> PV-reads (single wave: HW DS order; fence stops
    // the compiler reordering across the unsigned/half8 type pun)
    asm volatile("s_waitcnt lgkmcnt(0)" ::: "memory");
    __builtin_amdgcn_sched_barrier(0);
    // y^T += V_strip @ P^T ; each V fragment feeds both q-halves
    #pragma unroll
    for (int cc = 0; cc < 2; cc++) {
      const half8 pf0 = *(const half8*)&PL[0][qc * 72 + cc * 32 + g * 8];
      const half8 pf1 = *(const half8*)&PL[1][qc * 72 + cc * 32 + g * 8];
      const _Float16* vr = vgb + key0 + cc * 32;
      #pragma unroll
      for (int o = 0; o < 8; o++) {
        const half8 vf = *(const half8*)(vr + (size_t)o * 16 * NP);
        ya[0][o] = mfma16(vf, pf0, ya[0][o]);
        ya[1][o] = mfma16(vf, pf1, ya[1][o]);
      }
    }
    // keep next iteration's P-writes below this iteration's P-reads
    asm volatile("" ::: "memory");
  }
  float* ypb = yp + (size_t)(split * 2 + b) * 128 * NP;
  #pragma unroll
  for (int h = 0; h < 2; h++) {
    const int q = q0 + h * 16 + qc;
    #pragma unroll
    for (int o = 0; o < 8; o++)
      #pragma unroll
      for (int r = 0; r < 4; r++)
        ypb[(size_t)(o * 16 + g * 4 + r) * NP + q] = ya[h][o][r];
    if (g == 0) {
      ml[(size_t)((split * 2 + b) * 2 + 0) * NP + q] = m[h];
      ml[(size_t)((split * 2 + b) * 2 + 1) * NP + q] = l[h];
    }
  }
}

// merge 4 key-splits: Y = sum_s exp(m_s - M) yp_s / sum_s exp(m_s - M) l_s
__global__ __launch_bounds__(256) void attn_combine(const float* __restrict__ yp,
                                                    const float* __restrict__ ml,
                                                    float* __restrict__ Y) {
  const int b = blockIdx.y;
  const int q = blockIdx.x * 256 + threadIdx.x;
  if (q >= NN) return;
  float ms[4], ls[4], mx = -1e30f;
  #pragma unroll
  for (int s = 0; s < 4; s++) {
    ms[s] = ml[(size_t)((s * 2 + b) * 2 + 0) * NP + q];
    ls[s] = ml[(size_t)((s * 2 + b) * 2 + 1) * NP + q];
    mx = fmaxf(mx, ms[s]);
  }
  float wg[4], L = 0.f;
  #pragma unroll
  for (int s = 0; s < 4; s++) {
    wg[s] = __expf(ms[s] - mx);
    L += wg[s] * ls[s];
  }
  const float invL = 1.f / L;
  for (int o = 0; o < 128; o++) {
    float acc = 0.f;
    #pragma unroll
    for (int s = 0; s < 4; s++)
      acc += yp[(size_t)((s * 2 + b) * 128 + o) * NP + q] * wg[s];
    Y[(size_t)(b * 128 + o) * NN + q] = acc * invL;
  }
}

// ---------------- 3x3 conv as f16 MFMA implicit GEMM (validated round 5) ----------------
__global__ __launch_bounds__(256) void repack_w(const float* __restrict__ wh1,
                                                const float* __restrict__ hm1,
                                                const float* __restrict__ mv1,
                                                _Float16* __restrict__ Wwh,
                                                _Float16* __restrict__ Whm,
                                                _Float16* __restrict__ Wmv) {
  const int z = blockIdx.z;
  const int kb = blockIdx.x;
  const int cin = z == 0 ? 64 : 448;
  const int nkb = z == 0 ? 18 : 126;
  if (kb >= nkb) return;
  const float* src = z == 0 ? wh1 : (z == 1 ? hm1 : mv1);
  _Float16* dst = z == 0 ? Wwh : (z == 1 ? Whm : Wmv);
  const int t = threadIdx.x;
  const int oc = blockIdx.y * 8 + (t >> 5);
  const int j = t & 31;
  const int k = kb * 32 + j;
  const int tap = k / cin;
  const int cig = k - tap * cin;
  dst[((size_t)kb * 256 + oc) * 32 + j] = (_Float16)src[((size_t)oc * cin + cig) * 9 + tap];
}

template<int CIN, bool FINAL>
DI void conv_body(const _Float16* __restrict__ sb, const _Float16* __restrict__ wb,
                  int kb0, int nkb, const float* __restrict__ bias,
                  float* __restrict__ outp, int p0, int ocb) {
  __shared__ _Float16 AL[2][128][40];
  __shared__ _Float16 BL[2][64][40];
  const int tid = threadIdx.x;
  const int a_oc = tid >> 1, a_j = (tid & 1) * 16;
  const int b_pos = tid >> 2, b_seg = (tid & 3) * 8;
  const int opos = p0 + b_pos;
  const bool bvalid = opos < HW;
  const int op2 = bvalid ? opos : 0;
  const int r = op2 / 36, c = op2 - (op2 / 36) * 36;
  const int w = tid >> 6, lane = tid & 63;
  const int wm = w & 1, wn = w >> 1;
  const int frow = lane & 15, fg = lane >> 4;
  f32x4 acc[4][2] = {};

  auto stageA = [&](int bf, int kb) {
    const _Float16* src = wb + ((size_t)kb * 256 + ocb * 128 + a_oc) * 32 + a_j;
    *(half8*)&AL[bf][a_oc][a_j]     = *(const half8*)src;
    *(half8*)&AL[bf][a_oc][a_j + 8] = *(const half8*)(src + 8);
  };
  auto stageB = [&](int bf, int kb) {
    const int k0 = kb * 32;
    const int tap = k0 / CIN;
    const int rem = k0 - tap * CIN;
    const int fr = rem >> 6;
    const int ci0 = rem & 63;
    const int dy = tap / 3, dx = tap - (tap / 3) * 3;
    const int ppos = (r + dy) * PR + (c + dx);
    half8 v = {};
    if (bvalid)
      v = *(const half8*)(sb + ((size_t)fr * PADP + ppos) * 64 + ci0 + b_seg);
    *(half8*)&BL[bf][b_pos][b_seg] = v;
  };

  int buf = 0;
  stageA(0, kb0);
  stageB(0, kb0);
  __syncthreads();
  for (int it = 0; it < nkb; ++it) {
    if (it + 1 < nkb) {
      stageA(buf ^ 1, kb0 + it + 1);
      stageB(buf ^ 1, kb0 + it + 1);
    }
    half8 af[4], bf2[2];
    #pragma unroll
    for (int mf = 0; mf < 4; mf++)
      af[mf] = *(const half8*)&AL[buf][wm * 64 + mf * 16 + frow][fg * 8];
    #pragma unroll
    for (int nf = 0; nf < 2; nf++)
      bf2[nf] = *(const half8*)&BL[buf][wn * 32 + nf * 16 + frow][fg * 8];
    #pragma unroll
    for (int mf = 0; mf < 4; mf++)
      #pragma unroll
      for (int nf = 0; nf < 2; nf++)
        acc[mf][nf] = mfma16(af[mf], bf2[nf], acc[mf][nf]);
    __syncthreads();
    buf ^= 1;
  }
  #pragma unroll
  for (int mf = 0; mf < 4; mf++)
    #pragma unroll
    for (int nf = 0; nf < 2; nf++)
      #pragma unroll
      for (int rr = 0; rr < 4; rr++) {
        const int oc = ocb * 128 + wm * 64 + mf * 16 + fg * 4 + rr;
        const int pp = p0 + wn * 32 + nf * 16 + frow;
        if constexpr (FINAL) {
          if (pp < HW) {
            const float v = acc[mf][nf][rr] + bias[oc];
            outp[(size_t)oc * HW + pp] = v > 0.f ? v : 0.f;
          }
        } else {
          outp[(size_t)oc * 1344 + pp] = acc[mf][nf][rr];
        }
      }
}

__global__ __launch_bounds__(256) void conv_wh_mfma(const _Float16* __restrict__ Sp,
                                                    const _Float16* __restrict__ Wwh,
                                                    const float* __restrict__ bias,
                                                    float* __restrict__ WHR) {
  const int f = blockIdx.z;
  conv_body<64, true>(Sp + (size_t)f * PADP * 64, Wwh, 0, 18, bias,
                      WHR + (size_t)f * 256 * HW, blockIdx.x * 64, blockIdx.y);
}

__global__ __launch_bounds__(256) void conv_hm_mfma(const _Float16* __restrict__ Sp,
                                                    const _Float16* __restrict__ Whm,
                                                    const _Float16* __restrict__ Wmv,
                                                    float* __restrict__ part) {
  const int combo = blockIdx.z;            // split*4 + zi
  const int split = combo >> 2, zi = combo & 3;
  const int b = zi >> 1, head = zi & 1;
  conv_body<448, false>(Sp + (size_t)b * 7 * PADP * 64, head ? Wmv : Whm,
                        split * 42, 42, nullptr,
                        part + (size_t)combo * 256 * 1344, blockIdx.x * 64, blockIdx.y);
}

// oc-chunked: grid (6, 32), y = zi*8 + ocChunk -> 192 blocks (was 24)
__global__ __launch_bounds__(256) void conv_combine(const float* __restrict__ part,
                                                    const float* __restrict__ hm1_b,
                                                    const float* __restrict__ mv1_b,
                                                    float* __restrict__ HMR,
                                                    float* __restrict__ MVR) {
  const int zi = blockIdx.y >> 3;
  const int oc0 = (blockIdx.y & 7) * 32;
  const int p = blockIdx.x * 256 + threadIdx.x;
  if (p >= HW) return;
  const int b = zi >> 1, head = zi & 1;
  const float* bias = head ? mv1_b : hm1_b;
  float* outp = (head ? MVR : HMR) + (size_t)b * 256 * HW;
  for (int oc = oc0; oc < oc0 + 32; oc++) {
    float s = bias[oc];
    #pragma unroll
    for (int sp = 0; sp < 3; sp++)
      s += part[((size_t)(sp * 4 + zi) * 256 + oc) * 1344 + p];
    outp[(size_t)oc * HW + p] = s > 0.f ? s : 0.f;
  }
}

// ---------------- thin 1x1 heads ----------------
template<int MOUT, int MP, int EP>
__global__ __launch_bounds__(64) void head_k(const float* __restrict__ in,
                                             const float* __restrict__ w,
                                             const float* __restrict__ bias,
                                             float* __restrict__ out) {
  __shared__ float wl[256 * MP];
  const int f = blockIdx.y;
  const int p = blockIdx.x * 64 + threadIdx.x;
  for (int idx = threadIdx.x; idx < 256 * MP; idx += 64) {
    const int c = idx / MP, mm = idx % MP;
    wl[idx] = (mm < MOUT) ? w[mm * 256 + c] : 0.f;
  }
  __syncthreads();
  if (p >= HW) return;
  float acc[MP] = {};
  const float* ib = in + (size_t)f * 256 * HW + p;
  for (int c = 0; c < 256; c++) {
    const float v = ib[(size_t)c * HW];
    #pragma unroll
    for (int j = 0; j < MP; j++) acc[j] = fmaf(wl[c * MP + j], v, acc[j]);
  }
  if constexpr (EP == 0) {
    #pragma unroll
    for (int mm = 0; mm < MOUT; mm++) {
      const float v = acc[mm] + bias[mm];
      out[(size_t)(f * 24 + mm) * HW + p] = 1.f / (1.f + __expf(-v));
    }
  } else if constexpr (EP == 1) {
    #pragma unroll
    for (int mm = 0; mm < MOUT; mm++)
      out[62208 + (size_t)(f * 14 + mm) * HW + p] = acc[mm] + bias[mm];
  } else {
    const int bb = f / 7, kk = f % 7;
    #pragma unroll
    for (int mm = 0; mm < MOUT; mm++)
      out[98496 + (size_t)(bb * 14 + kk * 2 + mm) * HW + p] = acc[mm] + bias[mm];
  }
}

// ---------- workspace layout (bytes); liveness as in round 5 (validated) ----------
constexpr size_t OFF_Q    = 0;
constexpr size_t OFF_K    = 4653056;
constexpr size_t OFF_V    = 9306112;
constexpr size_t OFF_Y    = 13959168;
constexpr size_t OFF_Z    = 23248896;
constexpr size_t OFF_YP   = 23248896;
constexpr size_t OFF_ML   = 60473344;
constexpr size_t OFF_PART = 0;
constexpr size_t OFF_WHR  = 16515328;
constexpr size_t OFF_HMR  = 35094784;
constexpr size_t OFF_MVR  = 37748992;
constexpr size_t OFF_SP   = 41828352;
constexpr size_t OFF_WWH  = 61054976;
constexpr size_t OFF_WHM  = 61349888;
constexpr size_t OFF_WMV  = 63414272;

}  // namespace

extern "C" void kernel_launch(void* const* d_in, const int* in_sizes, int n_in,
                              void* d_out, int out_size, void* d_ws, size_t ws_size,
                              hipStream_t stream) {
  const float* x     = (const float*)d_in[0];
  const float* g_w   = (const float*)d_in[1];
  const float* g_b   = (const float*)d_in[2];
  const float* th_w  = (const float*)d_in[3];
  const float* th_b  = (const float*)d_in[4];
  const float* ph_w  = (const float*)d_in[5];
  const float* ph_b  = (const float*)d_in[6];
  const float* wz_w  = (const float*)d_in[7];
  const float* wz_b  = (const float*)d_in[8];
  const float* wz_g  = (const float*)d_in[9];
  const float* wz_be = (const float*)d_in[10];
  const float* wz_m  = (const float*)d_in[11];
  const float* wz_v  = (const float*)d_in[12];
  const float* sh_w  = (const float*)d_in[13];
  const float* sh_g  = (const float*)d_in[14];
  const float* sh_be = (const float*)d_in[15];
  const float* sh_m  = (const float*)d_in[16];
  const float* sh_v  = (const float*)d_in[17];
  const float* wh1_w = (const float*)d_in[18];
  const float* wh1_b = (const float*)d_in[19];
  const float* wh2_w = (const float*)d_in[20];
  const float* wh2_b = (const float*)d_in[21];
  const float* hm1_w = (const float*)d_in[22];
  const float* hm1_b = (const float*)d_in[23];
  const float* hmc_w = (const float*)d_in[24];
  const float* hmc_b = (const float*)d_in[25];
  const float* mv1_w = (const float*)d_in[26];
  const float* mv1_b = (const float*)d_in[27];
  const float* mv2_w = (const float*)d_in[28];
  const float* mv2_b = (const float*)d_in[29];
  float* out = (float*)d_out;
  char* ws = (char*)d_ws;

  _Float16* Q   = (_Float16*)(ws + OFF_Q);
  _Float16* Kb  = (_Float16*)(ws + OFF_K);
  _Float16* Vt  = (_Float16*)(ws + OFF_V);
  float*    Y   = (float*)(ws + OFF_Y);
  float*    Z   = (float*)(ws + OFF_Z);
  float*    YP  = (float*)(ws + OFF_YP);
  float*    ML  = (float*)(ws + OFF_ML);
  float*    PART= (float*)(ws + OFF_PART);
  float*    WHR = (float*)(ws + OFF_WHR);
  float*    HMR = (float*)(ws + OFF_HMR);
  float*    MVR = (float*)(ws + OFF_MVR);
  _Float16* Sp  = (_Float16*)(ws + OFF_SP);
  _Float16* Wwh = (_Float16*)(ws + OFF_WWH);
  _Float16* Whm = (_Float16*)(ws + OFF_WHM);
  _Float16* Wmv = (_Float16*)(ws + OFF_WMV);

  // 0. repack conv weights -> f16 k-blocked
  repack_w<<<dim3(126, 32, 3), 256, 0, stream>>>(wh1_w, hm1_w, mv1_w, Wwh, Whm, Wmv);
  // 1. fused theta/phi/g projections
  {
    ProjOp op{th_w, ph_w, g_w, th_b, ph_b, g_b, x, Q, Kb, Vt};
    gemm_t<256, 128, ProjOp><<<dim3(71, 6, 2), 256, 0, stream>>>(op);
  }
  // 2. flash attention (1-wave blocks, key-split x4) + combine -> Y
  attn_k<<<dim3(284 * 8), 64, 0, stream>>>(Q, Kb, Vt, YP, ML);
  attn_combine<<<dim3(36, 2), 256, 0, stream>>>(YP, ML, Y);
  // 3. zero padded-S (after YP dead), then Wz + BN + residual -> Z
  hipMemsetAsync(Sp, 0, (size_t)14 * PADP * 64 * 2, stream);
  {
    WzOp op{wz_w, wz_b, wz_g, wz_be, wz_m, wz_v, x, Y, Z};
    gemm_t<128, 128, WzOp><<<dim3(71, 4, 2), 256, 0, stream>>>(op);
  }
  // 4. shrink + BN -> padded f16 S
  {
    ShOp op{sh_w, sh_g, sh_be, sh_m, sh_v, Z, Sp};
    gemm_t<256, 64, ShOp><<<dim3(142, 1, 2), 256, 0, stream>>>(op);
  }
  // 5. wh 3x3 conv (MFMA) + bias + relu -> WHR
  conv_wh_mfma<<<dim3(21, 2, 14), 256, 0, stream>>>(Sp, Wwh, wh1_b, WHR);
  // 6. hm & mv 3x3 convs (MFMA, k-split x3) -> partials, then combine
  conv_hm_mfma<<<dim3(21, 2, 12), 256, 0, stream>>>(Sp, Whm, Wmv, PART);
  conv_combine<<<dim3(6, 32), 256, 0, stream>>>(PART, hm1_b, mv1_b, HMR, MVR);
  // 7. heads
  head_k<24, 24, 0><<<dim3(21, 2), 64, 0, stream>>>(HMR, hmc_w, hmc_b, out);
  head_k<14, 16, 1><<<dim3(21, 2), 64, 0, stream>>>(MVR, mv2_w, mv2_b, out);
  head_k<2, 2, 2><<<dim3(21, 14), 64, 0, stream>>>(WHR, wh2_w, wh2_b, out);
}

// Round 9
// 683.704 us; speedup vs baseline: 1.1025x; 1.1025x over previous
//
// MOC_Branch_KwithM on MI355X (gfx950).
// Pipeline: [proj GEMM -> Q/K/V f16] -> [flash attn: 4-wave blocks, QBLK=32/wave,
//   LDS-staged K/V, key-split x4 + combine] -> [Wz GEMM + BN + residual]
//   -> [shrink GEMM + BN -> padded f16 S] -> [3x3 convs as f16 MFMA implicit GEMM]
//   -> [1x1 heads].
#include <hip/hip_runtime.h>
#include <cstddef>

#define DI __device__ __forceinline__

typedef float    f32x4 __attribute__((ext_vector_type(4)));
typedef float    f32x2 __attribute__((ext_vector_type(2)));
typedef _Float16 half8 __attribute__((ext_vector_type(8)));

namespace {

constexpr int KF = 7;
constexpr int C  = 256;
constexpr int HW = 1296;     // 36*36
constexpr int NN = 9072;     // KF*HW
constexpr int NP = 9088;     // NN padded to multiple of 64
constexpr int IC = 128;
constexpr int PR = 38;       // padded spatial row
constexpr int PADP = PR * PR;  // 1444

DI f32x4 mfma16(half8 a, half8 b, f32x4 c) {
  return __builtin_amdgcn_mfma_f32_16x16x32_f16(a, b, c, 0, 0, 0);
}

DI unsigned pk2h(float a, float b) {
  unsigned short ua = __builtin_bit_cast(unsigned short, (_Float16)a);
  unsigned short ub = __builtin_bit_cast(unsigned short, (_Float16)b);
  return (unsigned)ua | ((unsigned)ub << 16);
}

// ---------------- generic tiled fp32 GEMM:  C[M,N] = A[M,K] @ B[K,N] ----------------
template<int K, int BN, class Op>
__global__ __launch_bounds__(256) void gemm_t(Op op) {
  constexpr int MN = BN / 16;
  __shared__ float As[16][64];
  __shared__ float Bs[16][BN];
  const int b  = blockIdx.z;
  const int m0 = blockIdx.y * 64;
  const int n0 = blockIdx.x * BN;
  const int tid = threadIdx.x;
  const int tx = tid & 15, ty = tid >> 4;
  float acc[4][MN] = {};
  for (int k0 = 0; k0 < K; k0 += 16) {
    {
      const int am = tid >> 2, ak = (tid & 3) * 4;
      #pragma unroll
      for (int i = 0; i < 4; i++) As[ak + i][am] = op.lda(b, m0 + am, k0 + ak + i);
    }
    {
      const int nn = tid % BN;
      const int kb = tid / BN;
      #pragma unroll
      for (int r = 0; r < (16 * BN) / 256; r++) {
        const int kk = kb + r * (256 / BN);
        Bs[kk][nn] = op.ldb(b, k0 + kk, n0 + nn);
      }
    }
    __syncthreads();
    #pragma unroll
    for (int kk = 0; kk < 16; kk++) {
      const f32x4 a = *(const f32x4*)&As[kk][ty * 4];
      f32x4 bv[MN / 4];
      #pragma unroll
      for (int j4 = 0; j4 < MN / 4; j4++) bv[j4] = *(const f32x4*)&Bs[kk][tx * MN + j4 * 4];
      #pragma unroll
      for (int i = 0; i < 4; i++)
        #pragma unroll
        for (int j = 0; j < MN; j++)
          acc[i][j] = fmaf(a[i], bv[j / 4][j & 3], acc[i][j]);
    }
    __syncthreads();
  }
  #pragma unroll
  for (int i = 0; i < 4; i++)
    #pragma unroll
    for (int j = 0; j < MN; j++)
      op.st(b, m0 + ty * 4 + i, n0 + tx * MN + j, acc[i][j]);
}

// proj: rows 0-127 = theta -> Q(n,128), 128-255 = phi -> Kb(n,128), 256-383 = g -> Vt(128,n)
struct ProjOp {
  const float *thw, *phw, *gw, *thb, *phb, *gb, *x;
  _Float16 *Q, *Kb, *Vt;
  DI float lda(int b, int m, int k) const {
    const int sel = m >> 7, r = m & 127;
    const float* w = sel == 0 ? thw : (sel == 1 ? phw : gw);
    return w[r * 256 + k];
  }
  DI float ldb(int b, int k, int n) const {
    if (n >= NN) return 0.f;
    const int fr = n / HW, hw = n % HW;
    return x[((b * KF + fr) * C + k) * HW + hw];
  }
  DI void st(int b, int m, int n, float v) const {
    if (n >= NN) return;
    const int sel = m >> 7, r = m & 127;
    const float* bias = sel == 0 ? thb : (sel == 1 ? phb : gb);
    const _Float16 h = (_Float16)(v + bias[r]);
    if (sel == 0)      Q [(size_t)(b * NP + n) * IC + r] = h;
    else if (sel == 1) Kb[(size_t)(b * NP + n) * IC + r] = h;
    else               Vt[(size_t)(b * IC + r) * NP + n] = h;
  }
};

// Wz @ y + bias -> BN -> + xn residual -> Z (b,256,NN)
struct WzOp {
  const float *w, *bias, *g, *be, *mu, *var, *x, *Y;
  float* Z;
  DI float lda(int b, int m, int k) const { return w[m * IC + k]; }
  DI float ldb(int b, int k, int n) const { return n < NN ? Y[(size_t)(b * IC + k) * NN + n] : 0.f; }
  DI void st(int b, int m, int n, float v) const {
    if (n >= NN) return;
    const float s = g[m] / sqrtf(var[m] + 1e-5f);
    float val = (v + bias[m] - mu[m]) * s + be[m];
    const int fr = n / HW, hw = n % HW;
    val += x[((b * KF + fr) * C + m) * HW + hw];
    Z[(size_t)(b * C + m) * NN + n] = val;
  }
};

// shrink (64x256) @ Z -> BN -> padded f16 S [14][PADP][64]
struct ShOp {
  const float *w, *g, *be, *mu, *var, *Z;
  _Float16* Sp;
  DI float lda(int b, int m, int k) const { return w[m * C + k]; }
  DI float ldb(int b, int k, int n) const { return n < NN ? Z[(size_t)(b * C + k) * NN + n] : 0.f; }
  DI void st(int b, int m, int n, float v) const {
    if (n >= NN) return;
    const float s = g[m] / sqrtf(var[m] + 1e-5f);
    const float val = (v - mu[m]) * s + be[m];
    const int fr = n / HW, hw = n % HW;
    const int r = hw / 36, c = hw % 36;
    Sp[((size_t)(b * KF + fr) * PADP + (r + 1) * PR + (c + 1)) * 64 + m] = (_Float16)val;
  }
};

// ---------------- flash attention ----------------
// 4 waves/block; each wave owns 32 q-rows (two 16-row halves) -> every K/V
// fragment read from LDS feeds TWO MFMAs, halving LDS traffic per q-row vs
// the round-5 structure. K/V tiles staged cooperatively (coalesced); combo =
// bid&7 pins each (split,batch) K/V slice (~1.16 MB) to one XCD's L2.
__global__ __launch_bounds__(256) void attn_k(const _Float16* __restrict__ Q,
                                              const _Float16* __restrict__ Kb,
                                              const _Float16* __restrict__ Vt,
                                              float* __restrict__ yp,
                                              float* __restrict__ ml) {
  __shared__ _Float16 KL[64 * 136];     // K-tile [key][ch]
  __shared__ _Float16 VL[128 * 72];     // V-tile [och][key]
  __shared__ _Float16 PL[4][2][16 * 72];  // per-wave, per-half P^T [q][key]
  const int bid = blockIdx.x;
  const int combo = bid & 7;
  const int split = combo >> 1, b = combo & 1;
  const int qb = bid >> 3;              // 0..70
  const int tid = threadIdx.x;
  const int w = tid >> 6, lane = tid & 63;
  const int qc = lane & 15, g = lane >> 4;
  const int q0 = qb * 128 + w * 32;     // wave's 32 q-rows (max row 9087 < NP)

  half8 qf[2][4];
  #pragma unroll
  for (int h = 0; h < 2; h++) {
    const _Float16* qbase = Q + (size_t)(b * NP + q0 + h * 16 + qc) * IC + g * 8;
    #pragma unroll
    for (int kc = 0; kc < 4; kc++) qf[h][kc] = *(const half8*)(qbase + kc * 32);
  }

  f32x4 ya[2][8];
  #pragma unroll
  for (int h = 0; h < 2; h++)
    #pragma unroll
    for (int o = 0; o < 8; o++) ya[h][o] = 0.f;
  float m[2] = {-1e30f, -1e30f}, l[2] = {0.f, 0.f};

  const int kt0 = split * 35 + (split < 2 ? split : 2);
  const int kt1 = kt0 + 35 + (split < 2 ? 1 : 0);
  const _Float16* kgb = Kb + (size_t)b * NP * IC;
  const _Float16* vgb = Vt + (size_t)b * IC * NP;

  for (int kt = kt0; kt < kt1; ++kt) {
    const int key0 = kt * 64;
    __syncthreads();   // previous tile's readers done
    // stage K tile: 64 keys x 128 ch (16B/thread, coalesced)
    #pragma unroll
    for (int it = 0; it < 4; it++) {
      const int i = it * 256 + tid;
      const int row = i >> 4, seg = i & 15;
      *(half8*)&KL[row * 136 + seg * 8] =
          *(const half8*)(kgb + (size_t)(key0 + row) * IC + seg * 8);
    }
    // stage V tile: 128 och x 64 keys
    #pragma unroll
    for (int it = 0; it < 4; it++) {
      const int i = it * 256 + tid;
      const int row = i >> 3, seg = i & 7;
      *(half8*)&VL[row * 72 + seg * 8] =
          *(const half8*)(vgb + (size_t)row * NP + key0 + seg * 8);
    }
    __syncthreads();   // tile visible

    const int nf = (kt == 141) ? 3 : 4;  // 9072 = 141*64+48 -> 3 valid frags in tail
    f32x4 st[2][4];
    #pragma unroll
    for (int f = 0; f < 4; f++) {
      if (f < nf) {
        const _Float16* kr = &KL[(f * 16 + qc) * 136 + g * 8];
        f32x4 a0 = {}; f32x4 a1 = {};
        #pragma unroll
        for (int kc = 0; kc < 4; kc++) {
          const half8 kf = *(const half8*)(kr + kc * 32);   // one read, two MFMAs
          a0 = mfma16(kf, qf[0][kc], a0);
          a1 = mfma16(kf, qf[1][kc], a1);
        }
        st[0][f] = a0; st[1][f] = a1;
      } else {
        st[0][f] = -1e30f; st[1][f] = -1e30f;  // masked keys -> exp() = 0
      }
    }
    // online softmax per q-half (stats live in this lane's q-column)
    #pragma unroll
    for (int h = 0; h < 2; h++) {
      float mt = -1e30f;
      #pragma unroll
      for (int f = 0; f < 4; f++)
        #pragma unroll
        for (int r = 0; r < 4; r++) mt = fmaxf(mt, st[h][f][r]);
      mt = fmaxf(mt, __shfl_xor(mt, 16));
      mt = fmaxf(mt, __shfl_xor(mt, 32));
      const float mn = fmaxf(m[h], mt);
      const float sc = __expf(m[h] - mn);
      float ls = 0.f;
      #pragma unroll
      for (int f = 0; f < 4; f++)
        #pragma unroll
        for (int r = 0; r < 4; r++) {
          const float e = __expf(st[h][f][r] - mn);
          st[h][f][r] = e;
          ls += e;
        }
      ls += __shfl_xor(ls, 16);
      ls += __shfl_xor(ls, 32);
      l[h] = l[h] * sc + ls;
      m[h] = mn;
      #pragma unroll
      for (int o = 0; o < 8; o++) ya[h][o] *= sc;
      // pack P^T -> per-wave LDS (key = f*16 + g*4 + rp*2 [+1])
      #pragma unroll
      for (int f = 0; f < 4; f++)
        #pragma unroll
        for (int rp = 0; rp < 2; rp++)
          *(unsigned*)&PL[w][h][qc * 72 + f * 16 + g * 4 + rp * 2] =
              pk2h(st[h][f][rp * 2], st[h][f][rp * 2 + 1]);
    }
    // order P pack-writes -> P reads (wave-level DS order; fence stops the
    // compiler reordering across the unsigned/half8 type pun)
    asm volatile("s_waitcnt lgkmcnt(0)" ::: "memory");
    __builtin_amdgcn_sched_barrier(0);
    // y^T += V_strip @ P^T ; each V fragment feeds both q-halves
    #pragma unroll
    for (int cc = 0; cc < 2; cc++) {
      const half8 pf0 = *(const half8*)&PL[w][0][qc * 72 + cc * 32 + g * 8];
      const half8 pf1 = *(const half8*)&PL[w][1][qc * 72 + cc * 32 + g * 8];
      #pragma unroll
      for (int o = 0; o < 8; o++) {
        const half8 vf = *(const half8*)&VL[(o * 16 + qc) * 72 + cc * 32 + g * 8];
        ya[0][o] = mfma16(vf, pf0, ya[0][o]);
        ya[1][o] = mfma16(vf, pf1, ya[1][o]);
      }
    }
  }
  float* ypb = yp + (size_t)(split * 2 + b) * 128 * NP;
  #pragma unroll
  for (int h = 0; h < 2; h++) {
    const int q = q0 + h * 16 + qc;
    #pragma unroll
    for (int o = 0; o < 8; o++)
      #pragma unroll
      for (int r = 0; r < 4; r++)
        ypb[(size_t)(o * 16 + g * 4 + r) * NP + q] = ya[h][o][r];
    if (g == 0) {
      ml[(size_t)((split * 2 + b) * 2 + 0) * NP + q] = m[h];
      ml[(size_t)((split * 2 + b) * 2 + 1) * NP + q] = l[h];
    }
  }
}

// merge 4 key-splits: Y = sum_s exp(m_s - M) yp_s / sum_s exp(m_s - M) l_s
// o-loop split across blockIdx.z (8 chunks of 16) -> 576 blocks (was 72,
// 0.28/CU -> parallelism-bound at ~40-80 us for 46 MB of traffic).
__global__ __launch_bounds__(256) void attn_combine(const float* __restrict__ yp,
                                                    const float* __restrict__ ml,
                                                    float* __restrict__ Y) {
  const int b = blockIdx.y;
  const int o0 = blockIdx.z * 16;
  const int q = blockIdx.x * 256 + threadIdx.x;
  if (q >= NN) return;
  float ms[4], ls[4], mx = -1e30f;
  #pragma unroll
  for (int s = 0; s < 4; s++) {
    ms[s] = ml[(size_t)((s * 2 + b) * 2 + 0) * NP + q];
    ls[s] = ml[(size_t)((s * 2 + b) * 2 + 1) * NP + q];
    mx = fmaxf(mx, ms[s]);
  }
  float wg[4], L = 0.f;
  #pragma unroll
  for (int s = 0; s < 4; s++) {
    wg[s] = __expf(ms[s] - mx);
    L += wg[s] * ls[s];
  }
  const float invL = 1.f / L;
  #pragma unroll
  for (int o = o0; o < o0 + 16; o++) {
    float acc = 0.f;
    #pragma unroll
    for (int s = 0; s < 4; s++)
      acc += yp[(size_t)((s * 2 + b) * 128 + o) * NP + q] * wg[s];
    Y[(size_t)(b * 128 + o) * NN + q] = acc * invL;
  }
}

// ---------------- 3x3 conv as f16 MFMA implicit GEMM (validated round 5) ----------------
__global__ __launch_bounds__(256) void repack_w(const float* __restrict__ wh1,
                                                const float* __restrict__ hm1,
                                                const float* __restrict__ mv1,
                                                _Float16* __restrict__ Wwh,
                                                _Float16* __restrict__ Whm,
                                                _Float16* __restrict__ Wmv) {
  const int z = blockIdx.z;
  const int kb = blockIdx.x;
  const int cin = z == 0 ? 64 : 448;
  const int nkb = z == 0 ? 18 : 126;
  if (kb >= nkb) return;
  const float* src = z == 0 ? wh1 : (z == 1 ? hm1 : mv1);
  _Float16* dst = z == 0 ? Wwh : (z == 1 ? Whm : Wmv);
  const int t = threadIdx.x;
  const int oc = blockIdx.y * 8 + (t >> 5);
  const int j = t & 31;
  const int k = kb * 32 + j;
  const int tap = k / cin;
  const int cig = k - tap * cin;
  dst[((size_t)kb * 256 + oc) * 32 + j] = (_Float16)src[((size_t)oc * cin + cig) * 9 + tap];
}

template<int CIN, bool FINAL>
DI void conv_body(const _Float16* __restrict__ sb, const _Float16* __restrict__ wb,
                  int kb0, int nkb, const float* __restrict__ bias,
                  float* __restrict__ outp, int p0, int ocb) {
  __shared__ _Float16 AL[2][128][40];
  __shared__ _Float16 BL[2][64][40];
  const int tid = threadIdx.x;
  const int a_oc = tid >> 1, a_j = (tid & 1) * 16;
  const int b_pos = tid >> 2, b_seg = (tid & 3) * 8;
  const int opos = p0 + b_pos;
  const bool bvalid = opos < HW;
  const int op2 = bvalid ? opos : 0;
  const int r = op2 / 36, c = op2 - (op2 / 36) * 36;
  const int w = tid >> 6, lane = tid & 63;
  const int wm = w & 1, wn = w >> 1;
  const int frow = lane & 15, fg = lane >> 4;
  f32x4 acc[4][2] = {};

  auto stageA = [&](int bf, int kb) {
    const _Float16* src = wb + ((size_t)kb * 256 + ocb * 128 + a_oc) * 32 + a_j;
    *(half8*)&AL[bf][a_oc][a_j]     = *(const half8*)src;
    *(half8*)&AL[bf][a_oc][a_j + 8] = *(const half8*)(src + 8);
  };
  auto stageB = [&](int bf, int kb) {
    const int k0 = kb * 32;
    const int tap = k0 / CIN;
    const int rem = k0 - tap * CIN;
    const int fr = rem >> 6;
    const int ci0 = rem & 63;
    const int dy = tap / 3, dx = tap - (tap / 3) * 3;
    const int ppos = (r + dy) * PR + (c + dx);
    half8 v = {};
    if (bvalid)
      v = *(const half8*)(sb + ((size_t)fr * PADP + ppos) * 64 + ci0 + b_seg);
    *(half8*)&BL[bf][b_pos][b_seg] = v;
  };

  int buf = 0;
  stageA(0, kb0);
  stageB(0, kb0);
  __syncthreads();
  for (int it = 0; it < nkb; ++it) {
    if (it + 1 < nkb) {
      stageA(buf ^ 1, kb0 + it + 1);
      stageB(buf ^ 1, kb0 + it + 1);
    }
    half8 af[4], bf2[2];
    #pragma unroll
    for (int mf = 0; mf < 4; mf++)
      af[mf] = *(const half8*)&AL[buf][wm * 64 + mf * 16 + frow][fg * 8];
    #pragma unroll
    for (int nf = 0; nf < 2; nf++)
      bf2[nf] = *(const half8*)&BL[buf][wn * 32 + nf * 16 + frow][fg * 8];
    #pragma unroll
    for (int mf = 0; mf < 4; mf++)
      #pragma unroll
      for (int nf = 0; nf < 2; nf++)
        acc[mf][nf] = mfma16(af[mf], bf2[nf], acc[mf][nf]);
    __syncthreads();
    buf ^= 1;
  }
  #pragma unroll
  for (int mf = 0; mf < 4; mf++)
    #pragma unroll
    for (int nf = 0; nf < 2; nf++)
      #pragma unroll
      for (int rr = 0; rr < 4; rr++) {
        const int oc = ocb * 128 + wm * 64 + mf * 16 + fg * 4 + rr;
        const int pp = p0 + wn * 32 + nf * 16 + frow;
        if constexpr (FINAL) {
          if (pp < HW) {
            const float v = acc[mf][nf][rr] + bias[oc];
            outp[(size_t)oc * HW + pp] = v > 0.f ? v : 0.f;
          }
        } else {
          outp[(size_t)oc * 1344 + pp] = acc[mf][nf][rr];
        }
      }
}

__global__ __launch_bounds__(256) void conv_wh_mfma(const _Float16* __restrict__ Sp,
                                                    const _Float16* __restrict__ Wwh,
                                                    const float* __restrict__ bias,
                                                    float* __restrict__ WHR) {
  const int f = blockIdx.z;
  conv_body<64, true>(Sp + (size_t)f * PADP * 64, Wwh, 0, 18, bias,
                      WHR + (size_t)f * 256 * HW, blockIdx.x * 64, blockIdx.y);
}

__global__ __launch_bounds__(256) void conv_hm_mfma(const _Float16* __restrict__ Sp,
                                                    const _Float16* __restrict__ Whm,
                                                    const _Float16* __restrict__ Wmv,
                                                    float* __restrict__ part) {
  const int combo = blockIdx.z;            // split*4 + zi
  const int split = combo >> 2, zi = combo & 3;
  const int b = zi >> 1, head = zi & 1;
  conv_body<448, false>(Sp + (size_t)b * 7 * PADP * 64, head ? Wmv : Whm,
                        split * 42, 42, nullptr,
                        part + (size_t)combo * 256 * 1344, blockIdx.x * 64, blockIdx.y);
}

// oc-chunked: grid (6, 32), y = zi*8 + ocChunk -> 192 blocks
__global__ __launch_bounds__(256) void conv_combine(const float* __restrict__ part,
                                                    const float* __restrict__ hm1_b,
                                                    const float* __restrict__ mv1_b,
                                                    float* __restrict__ HMR,
                                                    float* __restrict__ MVR) {
  const int zi = blockIdx.y >> 3;
  const int oc0 = (blockIdx.y & 7) * 32;
  const int p = blockIdx.x * 256 + threadIdx.x;
  if (p >= HW) return;
  const int b = zi >> 1, head = zi & 1;
  const float* bias = head ? mv1_b : hm1_b;
  float* outp = (head ? MVR : HMR) + (size_t)b * 256 * HW;
  for (int oc = oc0; oc < oc0 + 32; oc++) {
    float s = bias[oc];
    #pragma unroll
    for (int sp = 0; sp < 3; sp++)
      s += part[((size_t)(sp * 4 + zi) * 256 + oc) * 1344 + p];
    outp[(size_t)oc * HW + p] = s > 0.f ? s : 0.f;
  }
}

// ---------------- thin 1x1 heads ----------------
template<int MOUT, int MP, int EP>
__global__ __launch_bounds__(64) void head_k(const float* __restrict__ in,
                                             const float* __restrict__ w,
                                             const float* __restrict__ bias,
                                             float* __restrict__ out) {
  __shared__ float wl[256 * MP];
  const int f = blockIdx.y;
  const int p = blockIdx.x * 64 + threadIdx.x;
  for (int idx = threadIdx.x; idx < 256 * MP; idx += 64) {
    const int c = idx / MP, mm = idx % MP;
    wl[idx] = (mm < MOUT) ? w[mm * 256 + c] : 0.f;
  }
  __syncthreads();
  if (p >= HW) return;
  float acc[MP] = {};
  const float* ib = in + (size_t)f * 256 * HW + p;
  for (int c = 0; c < 256; c++) {
    const float v = ib[(size_t)c * HW];
    #pragma unroll
    for (int j = 0; j < MP; j++) acc[j] = fmaf(wl[c * MP + j], v, acc[j]);
  }
  if constexpr (EP == 0) {
    #pragma unroll
    for (int mm = 0; mm < MOUT; mm++) {
      const float v = acc[mm] + bias[mm];
      out[(size_t)(f * 24 + mm) * HW + p] = 1.f / (1.f + __expf(-v));
    }
  } else if constexpr (EP == 1) {
    #pragma unroll
    for (int mm = 0; mm < MOUT; mm++)
      out[62208 + (size_t)(f * 14 + mm) * HW + p] = acc[mm] + bias[mm];
  } else {
    const int bb = f / 7, kk = f % 7;
    #pragma unroll
    for (int mm = 0; mm < MOUT; mm++)
      out[98496 + (size_t)(bb * 14 + kk * 2 + mm) * HW + p] = acc[mm] + bias[mm];
  }
}

// ---------- workspace layout (bytes); liveness as in round 5 (validated) ----------
constexpr size_t OFF_Q    = 0;
constexpr size_t OFF_K    = 4653056;
constexpr size_t OFF_V    = 9306112;
constexpr size_t OFF_Y    = 13959168;
constexpr size_t OFF_Z    = 23248896;
constexpr size_t OFF_YP   = 23248896;
constexpr size_t OFF_ML   = 60473344;
constexpr size_t OFF_PART = 0;
constexpr size_t OFF_WHR  = 16515328;
constexpr size_t OFF_HMR  = 35094784;
constexpr size_t OFF_MVR  = 37748992;
constexpr size_t OFF_SP   = 41828352;
constexpr size_t OFF_WWH  = 61054976;
constexpr size_t OFF_WHM  = 61349888;
constexpr size_t OFF_WMV  = 63414272;

}  // namespace

extern "C" void kernel_launch(void* const* d_in, const int* in_sizes, int n_in,
                              void* d_out, int out_size, void* d_ws, size_t ws_size,
                              hipStream_t stream) {
  const float* x     = (const float*)d_in[0];
  const float* g_w   = (const float*)d_in[1];
  const float* g_b   = (const float*)d_in[2];
  const float* th_w  = (const float*)d_in[3];
  const float* th_b  = (const float*)d_in[4];
  const float* ph_w  = (const float*)d_in[5];
  const float* ph_b  = (const float*)d_in[6];
  const float* wz_w  = (const float*)d_in[7];
  const float* wz_b  = (const float*)d_in[8];
  const float* wz_g  = (const float*)d_in[9];
  const float* wz_be = (const float*)d_in[10];
  const float* wz_m  = (const float*)d_in[11];
  const float* wz_v  = (const float*)d_in[12];
  const float* sh_w  = (const float*)d_in[13];
  const float* sh_g  = (const float*)d_in[14];
  const float* sh_be = (const float*)d_in[15];
  const float* sh_m  = (const float*)d_in[16];
  const float* sh_v  = (const float*)d_in[17];
  const float* wh1_w = (const float*)d_in[18];
  const float* wh1_b = (const float*)d_in[19];
  const float* wh2_w = (const float*)d_in[20];
  const float* wh2_b = (const float*)d_in[21];
  const float* hm1_w = (const float*)d_in[22];
  const float* hm1_b = (const float*)d_in[23];
  const float* hmc_w = (const float*)d_in[24];
  const float* hmc_b = (const float*)d_in[25];
  const float* mv1_w = (const float*)d_in[26];
  const float* mv1_b = (const float*)d_in[27];
  const float* mv2_w = (const float*)d_in[28];
  const float* mv2_b = (const float*)d_in[29];
  float* out = (float*)d_out;
  char* ws = (char*)d_ws;

  _Float16* Q   = (_Float16*)(ws + OFF_Q);
  _Float16* Kb  = (_Float16*)(ws + OFF_K);
  _Float16* Vt  = (_Float16*)(ws + OFF_V);
  float*    Y   = (float*)(ws + OFF_Y);
  float*    Z   = (float*)(ws + OFF_Z);
  float*    YP  = (float*)(ws + OFF_YP);
  float*    ML  = (float*)(ws + OFF_ML);
  float*    PART= (float*)(ws + OFF_PART);
  float*    WHR = (float*)(ws + OFF_WHR);
  float*    HMR = (float*)(ws + OFF_HMR);
  float*    MVR = (float*)(ws + OFF_MVR);
  _Float16* Sp  = (_Float16*)(ws + OFF_SP);
  _Float16* Wwh = (_Float16*)(ws + OFF_WWH);
  _Float16* Whm = (_Float16*)(ws + OFF_WHM);
  _Float16* Wmv = (_Float16*)(ws + OFF_WMV);

  // 0. repack conv weights -> f16 k-blocked
  repack_w<<<dim3(126, 32, 3), 256, 0, stream>>>(wh1_w, hm1_w, mv1_w, Wwh, Whm, Wmv);
  // 1. fused theta/phi/g projections
  {
    ProjOp op{th_w, ph_w, g_w, th_b, ph_b, g_b, x, Q, Kb, Vt};
    gemm_t<256, 128, ProjOp><<<dim3(71, 6, 2), 256, 0, stream>>>(op);
  }
  // 2. flash attention (4-wave blocks, 128 q/block, key-split x4) + combine -> Y
  attn_k<<<dim3(71 * 8), 256, 0, stream>>>(Q, Kb, Vt, YP, ML);
  attn_combine<<<dim3(36, 2, 8), 256, 0, stream>>>(YP, ML, Y);
  // 3. zero padded-S (after YP dead), then Wz + BN + residual -> Z
  hipMemsetAsync(Sp, 0, (size_t)14 * PADP * 64 * 2, stream);
  {
    WzOp op{wz_w, wz_b, wz_g, wz_be, wz_m, wz_v, x, Y, Z};
    gemm_t<128, 128, WzOp><<<dim3(71, 4, 2), 256, 0, stream>>>(op);
  }
  // 4. shrink + BN -> padded f16 S
  {
    ShOp op{sh_w, sh_g, sh_be, sh_m, sh_v, Z, Sp};
    gemm_t<256, 64, ShOp><<<dim3(142, 1, 2), 256, 0, stream>>>(op);
  }
  // 5. wh 3x3 conv (MFMA) + bias + relu -> WHR
  conv_wh_mfma<<<dim3(21, 2, 14), 256, 0, stream>>>(Sp, Wwh, wh1_b, WHR);
  // 6. hm & mv 3x3 convs (MFMA, k-split x3) -> partials, then combine
  conv_hm_mfma<<<dim3(21, 2, 12), 256, 0, stream>>>(Sp, Whm, Wmv, PART);
  conv_combine<<<dim3(6, 32), 256, 0, stream>>>(PART, hm1_b, mv1_b, HMR, MVR);
  // 7. heads
  head_k<24, 24, 0><<<dim3(21, 2), 64, 0, stream>>>(HMR, hmc_w, hmc_b, out);
  head_k<14, 16, 1><<<dim3(21, 2), 64, 0, stream>>>(MVR, mv2_w, mv2_b, out);
  head_k<2, 2, 2><<<dim3(21, 14), 64, 0, stream>>>(WHR, wh2_w, wh2_b, out);
}

// Round 12
// 595.503 us; speedup vs baseline: 1.2658x; 1.1481x over previous
//
// MOC_Branch_KwithM on MI355X (gfx950).
// Pipeline: [proj GEMM -> Q/K/V f16] -> [flash attn: 4-wave blocks, QBLK=16/wave,
//   XOR-swizzled LDS K/V tiles (bank-conflict-free), key-split x4 + z-split combine]
//   -> [Wz GEMM + BN + residual] -> [shrink GEMM + BN -> padded f16 S]
//   -> [3x3 convs as f16 MFMA implicit GEMM] -> [1x1 heads].
#include <hip/hip_runtime.h>
#include <cstddef>

#define DI __device__ __forceinline__

typedef float    f32x4 __attribute__((ext_vector_type(4)));
typedef float    f32x2 __attribute__((ext_vector_type(2)));
typedef _Float16 half8 __attribute__((ext_vector_type(8)));

namespace {

constexpr int KF = 7;
constexpr int C  = 256;
constexpr int HW = 1296;     // 36*36
constexpr int NN = 9072;     // KF*HW
constexpr int NP = 9088;     // NN padded to multiple of 64
constexpr int IC = 128;
constexpr int PR = 38;       // padded spatial row
constexpr int PADP = PR * PR;  // 1444

DI f32x4 mfma16(half8 a, half8 b, f32x4 c) {
  return __builtin_amdgcn_mfma_f32_16x16x32_f16(a, b, c, 0, 0, 0);
}

DI unsigned pk2h(float a, float b) {
  unsigned short ua = __builtin_bit_cast(unsigned short, (_Float16)a);
  unsigned short ub = __builtin_bit_cast(unsigned short, (_Float16)b);
  return (unsigned)ua | ((unsigned)ub << 16);
}

// ---------------- generic tiled fp32 GEMM:  C[M,N] = A[M,K] @ B[K,N] ----------------
template<int K, int BN, class Op>
__global__ __launch_bounds__(256) void gemm_t(Op op) {
  constexpr int MN = BN / 16;
  __shared__ float As[16][64];
  __shared__ float Bs[16][BN];
  const int b  = blockIdx.z;
  const int m0 = blockIdx.y * 64;
  const int n0 = blockIdx.x * BN;
  const int tid = threadIdx.x;
  const int tx = tid & 15, ty = tid >> 4;
  float acc[4][MN] = {};
  for (int k0 = 0; k0 < K; k0 += 16) {
    {
      const int am = tid >> 2, ak = (tid & 3) * 4;
      #pragma unroll
      for (int i = 0; i < 4; i++) As[ak + i][am] = op.lda(b, m0 + am, k0 + ak + i);
    }
    {
      const int nn = tid % BN;
      const int kb = tid / BN;
      #pragma unroll
      for (int r = 0; r < (16 * BN) / 256; r++) {
        const int kk = kb + r * (256 / BN);
        Bs[kk][nn] = op.ldb(b, k0 + kk, n0 + nn);
      }
    }
    __syncthreads();
    #pragma unroll
    for (int kk = 0; kk < 16; kk++) {
      const f32x4 a = *(const f32x4*)&As[kk][ty * 4];
      f32x4 bv[MN / 4];
      #pragma unroll
      for (int j4 = 0; j4 < MN / 4; j4++) bv[j4] = *(const f32x4*)&Bs[kk][tx * MN + j4 * 4];
      #pragma unroll
      for (int i = 0; i < 4; i++)
        #pragma unroll
        for (int j = 0; j < MN; j++)
          acc[i][j] = fmaf(a[i], bv[j / 4][j & 3], acc[i][j]);
    }
    __syncthreads();
  }
  #pragma unroll
  for (int i = 0; i < 4; i++)
    #pragma unroll
    for (int j = 0; j < MN; j++)
      op.st(b, m0 + ty * 4 + i, n0 + tx * MN + j, acc[i][j]);
}

// proj: rows 0-127 = theta -> Q(n,128), 128-255 = phi -> Kb(n,128), 256-383 = g -> Vt(128,n)
struct ProjOp {
  const float *thw, *phw, *gw, *thb, *phb, *gb, *x;
  _Float16 *Q, *Kb, *Vt;
  DI float lda(int b, int m, int k) const {
    const int sel = m >> 7, r = m & 127;
    const float* w = sel == 0 ? thw : (sel == 1 ? phw : gw);
    return w[r * 256 + k];
  }
  DI float ldb(int b, int k, int n) const {
    if (n >= NN) return 0.f;
    const int fr = n / HW, hw = n % HW;
    return x[((b * KF + fr) * C + k) * HW + hw];
  }
  DI void st(int b, int m, int n, float v) const {
    if (n >= NN) return;
    const int sel = m >> 7, r = m & 127;
    const float* bias = sel == 0 ? thb : (sel == 1 ? phb : gb);
    const _Float16 h = (_Float16)(v + bias[r]);
    if (sel == 0)      Q [(size_t)(b * NP + n) * IC + r] = h;
    else if (sel == 1) Kb[(size_t)(b * NP + n) * IC + r] = h;
    else               Vt[(size_t)(b * IC + r) * NP + n] = h;
  }
};

// Wz @ y + bias -> BN -> + xn residual -> Z (b,256,NN)
struct WzOp {
  const float *w, *bias, *g, *be, *mu, *var, *x, *Y;
  float* Z;
  DI float lda(int b, int m, int k) const { return w[m * IC + k]; }
  DI float ldb(int b, int k, int n) const { return n < NN ? Y[(size_t)(b * IC + k) * NN + n] : 0.f; }
  DI void st(int b, int m, int n, float v) const {
    if (n >= NN) return;
    const float s = g[m] / sqrtf(var[m] + 1e-5f);
    float val = (v + bias[m] - mu[m]) * s + be[m];
    const int fr = n / HW, hw = n % HW;
    val += x[((b * KF + fr) * C + m) * HW + hw];
    Z[(size_t)(b * C + m) * NN + n] = val;
  }
};

// shrink (64x256) @ Z -> BN -> padded f16 S [14][PADP][64]
struct ShOp {
  const float *w, *g, *be, *mu, *var, *Z;
  _Float16* Sp;
  DI float lda(int b, int m, int k) const { return w[m * C + k]; }
  DI float ldb(int b, int k, int n) const { return n < NN ? Z[(size_t)(b * C + k) * NN + n] : 0.f; }
  DI void st(int b, int m, int n, float v) const {
    if (n >= NN) return;
    const float s = g[m] / sqrtf(var[m] + 1e-5f);
    const float val = (v - mu[m]) * s + be[m];
    const int fr = n / HW, hw = n % HW;
    const int r = hw / 36, c = hw % 36;
    Sp[((size_t)(b * KF + fr) * PADP + (r + 1) * PR + (c + 1)) * 64 + m] = (_Float16)val;
  }
};

// ---------------- flash attention ----------------
// Round-5 structure (measured 194 us): 4 waves/block, 16 q-rows/wave, 1136
// blocks, combo=bid&7 XCD-pins each (split,batch) K/V slice to one L2.
// NEW: K/V LDS tiles are unpadded and XOR-SWIZZLED (T2): 16B slot index is
// XORed with (row & (slots-1)) on BOTH stage-write and frag-read. Removes the
// 16-way same-bank-column serialization (r5: 2.45e7 conflict cycles).
__global__ __launch_bounds__(256) void attn_k(const _Float16* __restrict__ Q,
                                              const _Float16* __restrict__ Kb,
                                              const _Float16* __restrict__ Vt,
                                              float* __restrict__ yp,
                                              float* __restrict__ ml) {
  __shared__ _Float16 KL[64 * 128];     // K-tile [key][ch], swizzled 16B slots
  __shared__ _Float16 VL[128 * 64];     // V-tile [och][key], swizzled
  __shared__ _Float16 PL[4][16 * 72];   // per-wave P^T [q][key] (144B rows, 16B-aligned)
  const int bid = blockIdx.x;
  const int combo = bid & 7;
  const int split = combo >> 1, b = combo & 1;
  const int qb = bid >> 3;              // 0..141
  const int tid = threadIdx.x;
  const int w = tid >> 6, lane = tid & 63;
  const int qc = lane & 15, g = lane >> 4;
  const int q = qb * 64 + w * 16 + qc;  // this lane's query row (max 9087 < NP)

  half8 qf[4];
  {
    const _Float16* qbase = Q + (size_t)(b * NP + q) * IC + g * 8;
    #pragma unroll
    for (int kc = 0; kc < 4; kc++) qf[kc] = *(const half8*)(qbase + kc * 32);
  }

  f32x4 ya[8];
  #pragma unroll
  for (int o = 0; o < 8; o++) ya[o] = 0.f;
  float m = -1e30f, l = 0.f;
  _Float16* pw = PL[w];

  const int kt0 = split * 35 + (split < 2 ? split : 2);
  const int kt1 = kt0 + 35 + (split < 2 ? 1 : 0);
  const _Float16* kgb = Kb + (size_t)b * NP * IC;
  const _Float16* vgb = Vt + (size_t)b * IC * NP;

  for (int kt = kt0; kt < kt1; ++kt) {
    const int key0 = kt * 64;
    __syncthreads();   // previous tile's readers done
    // stage K tile: 64 keys x 128 ch; write slot = seg ^ (row&15)
    #pragma unroll
    for (int it = 0; it < 4; it++) {
      const int i = it * 256 + tid;
      const int row = i >> 4, seg = i & 15;
      *(half8*)&KL[row * 128 + (seg ^ (row & 15)) * 8] =
          *(const half8*)(kgb + (size_t)(key0 + row) * IC + seg * 8);
    }
    // stage V tile: 128 och x 64 keys; write slot = seg ^ (row&7)
    #pragma unroll
    for (int it = 0; it < 4; it++) {
      const int i = it * 256 + tid;
      const int row = i >> 3, seg = i & 7;
      *(half8*)&VL[row * 64 + (seg ^ (row & 7)) * 8] =
          *(const half8*)(vgb + (size_t)row * NP + key0 + seg * 8);
    }
    __syncthreads();   // tile visible

    const int nf = (kt == 141) ? 3 : 4;  // 9072 = 141*64+48 -> 3 valid frags in tail
    f32x4 st[4];
    #pragma unroll
    for (int f = 0; f < 4; f++) {
      if (f < nf) {
        f32x4 acc = {};
        const int krow = f * 16 + qc;       // krow & 15 == qc
        #pragma unroll
        for (int kc = 0; kc < 4; kc++) {
          const half8 kf = *(const half8*)&KL[krow * 128 + ((g + 4 * kc) ^ qc) * 8];
          acc = mfma16(kf, qf[kc], acc);
        }
        st[f] = acc;
      } else {
        st[f] = -1e30f;  // masked keys -> exp() = 0
      }
    }
    // online softmax stats for this lane's q-column
    float mt = -1e30f;
    #pragma unroll
    for (int f = 0; f < 4; f++)
      #pragma unroll
      for (int r = 0; r < 4; r++) mt = fmaxf(mt, st[f][r]);
    mt = fmaxf(mt, __shfl_xor(mt, 16));
    mt = fmaxf(mt, __shfl_xor(mt, 32));
    const float mn = fmaxf(m, mt);
    const float sc = __expf(m - mn);
    float ls = 0.f;
    #pragma unroll
    for (int f = 0; f < 4; f++)
      #pragma unroll
      for (int r = 0; r < 4; r++) {
        const float e = __expf(st[f][r] - mn);
        st[f][r] = e;
        ls += e;
      }
    ls += __shfl_xor(ls, 16);
    ls += __shfl_xor(ls, 32);
    l = l * sc + ls;
    m = mn;
    #pragma unroll
    for (int o = 0; o < 8; o++) ya[o] *= sc;
    // pack P^T -> per-wave LDS (key = f*16 + g*4 + rp*2 [+1])
    #pragma unroll
    for (int f = 0; f < 4; f++)
      #pragma unroll
      for (int rp = 0; rp < 2; rp++)
        *(unsigned*)&pw[qc * 72 + f * 16 + g * 4 + rp * 2] =
            pk2h(st[f][rp * 2], st[f][rp * 2 + 1]);
    // order P pack-writes -> P reads (wave-level DS order; fence stops the
    // compiler reordering across the unsigned/half8 type pun)
    asm volatile("s_waitcnt lgkmcnt(0)" ::: "memory");
    __builtin_amdgcn_sched_barrier(0);
    // y^T += V_strip @ P^T  (V read swizzled: vrow & 7 == qc & 7)
    #pragma unroll
    for (int cc = 0; cc < 2; cc++) {
      const half8 pf = *(const half8*)&pw[qc * 72 + cc * 32 + g * 8];
      #pragma unroll
      for (int o = 0; o < 8; o++) {
        const int vrow = o * 16 + qc;
        const half8 vf = *(const half8*)&VL[vrow * 64 + ((g + 4 * cc) ^ (qc & 7)) * 8];
        ya[o] = mfma16(vf, pf, ya[o]);
      }
    }
  }
  float* ypb = yp + (size_t)(split * 2 + b) * 128 * NP;
  #pragma unroll
  for (int o = 0; o < 8; o++)
    #pragma unroll
    for (int r = 0; r < 4; r++)
      ypb[(size_t)(o * 16 + g * 4 + r) * NP + q] = ya[o][r];
  if (g == 0) {
    ml[(size_t)((split * 2 + b) * 2 + 0) * NP + q] = m;
    ml[(size_t)((split * 2 + b) * 2 + 1) * NP + q] = l;
  }
}

// merge 4 key-splits: Y = sum_s exp(m_s - M) yp_s / sum_s exp(m_s - M) l_s
// o-loop split across blockIdx.z (8 chunks of 16) -> 576 blocks (validated r9).
__global__ __launch_bounds__(256) void attn_combine(const float* __restrict__ yp,
                                                    const float* __restrict__ ml,
                                                    float* __restrict__ Y) {
  const int b = blockIdx.y;
  const int o0 = blockIdx.z * 16;
  const int q = blockIdx.x * 256 + threadIdx.x;
  if (q >= NN) return;
  float ms[4], ls[4], mx = -1e30f;
  #pragma unroll
  for (int s = 0; s < 4; s++) {
    ms[s] = ml[(size_t)((s * 2 + b) * 2 + 0) * NP + q];
    ls[s] = ml[(size_t)((s * 2 + b) * 2 + 1) * NP + q];
    mx = fmaxf(mx, ms[s]);
  }
  float wg[4], L = 0.f;
  #pragma unroll
  for (int s = 0; s < 4; s++) {
    wg[s] = __expf(ms[s] - mx);
    L += wg[s] * ls[s];
  }
  const float invL = 1.f / L;
  #pragma unroll
  for (int o = o0; o < o0 + 16; o++) {
    float acc = 0.f;
    #pragma unroll
    for (int s = 0; s < 4; s++)
      acc += yp[(size_t)((s * 2 + b) * 128 + o) * NP + q] * wg[s];
    Y[(size_t)(b * 128 + o) * NN + q] = acc * invL;
  }
}

// ---------------- 3x3 conv as f16 MFMA implicit GEMM (validated round 5) ----------------
__global__ __launch_bounds__(256) void repack_w(const float* __restrict__ wh1,
                                                const float* __restrict__ hm1,
                                                const float* __restrict__ mv1,
                                                _Float16* __restrict__ Wwh,
                                                _Float16* __restrict__ Whm,
                                                _Float16* __restrict__ Wmv) {
  const int z = blockIdx.z;
  const int kb = blockIdx.x;
  const int cin = z == 0 ? 64 : 448;
  const int nkb = z == 0 ? 18 : 126;
  if (kb >= nkb) return;
  const float* src = z == 0 ? wh1 : (z == 1 ? hm1 : mv1);
  _Float16* dst = z == 0 ? Wwh : (z == 1 ? Whm : Wmv);
  const int t = threadIdx.x;
  const int oc = blockIdx.y * 8 + (t >> 5);
  const int j = t & 31;
  const int k = kb * 32 + j;
  const int tap = k / cin;
  const int cig = k - tap * cin;
  dst[((size_t)kb * 256 + oc) * 32 + j] = (_Float16)src[((size_t)oc * cin + cig) * 9 + tap];
}

template<int CIN, bool FINAL>
DI void conv_body(const _Float16* __restrict__ sb, const _Float16* __restrict__ wb,
                  int kb0, int nkb, const float* __restrict__ bias,
                  float* __restrict__ outp, int p0, int ocb) {
  __shared__ _Float16 AL[2][128][40];
  __shared__ _Float16 BL[2][64][40];
  const int tid = threadIdx.x;
  const int a_oc = tid >> 1, a_j = (tid & 1) * 16;
  const int b_pos = tid >> 2, b_seg = (tid & 3) * 8;
  const int opos = p0 + b_pos;
  const bool bvalid = opos < HW;
  const int op2 = bvalid ? opos : 0;
  const int r = op2 / 36, c = op2 - (op2 / 36) * 36;
  const int w = tid >> 6, lane = tid & 63;
  const int wm = w & 1, wn = w >> 1;
  const int frow = lane & 15, fg = lane >> 4;
  f32x4 acc[4][2] = {};

  auto stageA = [&](int bf, int kb) {
    const _Float16* src = wb + ((size_t)kb * 256 + ocb * 128 + a_oc) * 32 + a_j;
    *(half8*)&AL[bf][a_oc][a_j]     = *(const half8*)src;
    *(half8*)&AL[bf][a_oc][a_j + 8] = *(const half8*)(src + 8);
  };
  auto stageB = [&](int bf, int kb) {
    const int k0 = kb * 32;
    const int tap = k0 / CIN;
    const int rem = k0 - tap * CIN;
    const int fr = rem >> 6;
    const int ci0 = rem & 63;
    const int dy = tap / 3, dx = tap - (tap / 3) * 3;
    const int ppos = (r + dy) * PR + (c + dx);
    half8 v = {};
    if (bvalid)
      v = *(const half8*)(sb + ((size_t)fr * PADP + ppos) * 64 + ci0 + b_seg);
    *(half8*)&BL[bf][b_pos][b_seg] = v;
  };

  int buf = 0;
  stageA(0, kb0);
  stageB(0, kb0);
  __syncthreads();
  for (int it = 0; it < nkb; ++it) {
    if (it + 1 < nkb) {
      stageA(buf ^ 1, kb0 + it + 1);
      stageB(buf ^ 1, kb0 + it + 1);
    }
    half8 af[4], bf2[2];
    #pragma unroll
    for (int mf = 0; mf < 4; mf++)
      af[mf] = *(const half8*)&AL[buf][wm * 64 + mf * 16 + frow][fg * 8];
    #pragma unroll
    for (int nf = 0; nf < 2; nf++)
      bf2[nf] = *(const half8*)&BL[buf][wn * 32 + nf * 16 + frow][fg * 8];
    #pragma unroll
    for (int mf = 0; mf < 4; mf++)
      #pragma unroll
      for (int nf = 0; nf < 2; nf++)
        acc[mf][nf] = mfma16(af[mf], bf2[nf], acc[mf][nf]);
    __syncthreads();
    buf ^= 1;
  }
  #pragma unroll
  for (int mf = 0; mf < 4; mf++)
    #pragma unroll
    for (int nf = 0; nf < 2; nf++)
      #pragma unroll
      for (int rr = 0; rr < 4; rr++) {
        const int oc = ocb * 128 + wm * 64 + mf * 16 + fg * 4 + rr;
        const int pp = p0 + wn * 32 + nf * 16 + frow;
        if constexpr (FINAL) {
          if (pp < HW) {
            const float v = acc[mf][nf][rr] + bias[oc];
            outp[(size_t)oc * HW + pp] = v > 0.f ? v : 0.f;
          }
        } else {
          outp[(size_t)oc * 1344 + pp] = acc[mf][nf][rr];
        }
      }
}

__global__ __launch_bounds__(256) void conv_wh_mfma(const _Float16* __restrict__ Sp,
                                                    const _Float16* __restrict__ Wwh,
                                                    const float* __restrict__ bias,
                                                    float* __restrict__ WHR) {
  const int f = blockIdx.z;
  conv_body<64, true>(Sp + (size_t)f * PADP * 64, Wwh, 0, 18, bias,
                      WHR + (size_t)f * 256 * HW, blockIdx.x * 64, blockIdx.y);
}

__global__ __launch_bounds__(256) void conv_hm_mfma(const _Float16* __restrict__ Sp,
                                                    const _Float16* __restrict__ Whm,
                                                    const _Float16* __restrict__ Wmv,
                                                    float* __restrict__ part) {
  const int combo = blockIdx.z;            // split*4 + zi
  const int split = combo >> 2, zi = combo & 3;
  const int b = zi >> 1, head = zi & 1;
  conv_body<448, false>(Sp + (size_t)b * 7 * PADP * 64, head ? Wmv : Whm,
                        split * 42, 42, nullptr,
                        part + (size_t)combo * 256 * 1344, blockIdx.x * 64, blockIdx.y);
}

// oc-chunked: grid (6, 32), y = zi*8 + ocChunk -> 192 blocks (validated r9)
__global__ __launch_bounds__(256) void conv_combine(const float* __restrict__ part,
                                                    const float* __restrict__ hm1_b,
                                                    const float* __restrict__ mv1_b,
                                                    float* __restrict__ HMR,
                                                    float* __restrict__ MVR) {
  const int zi = blockIdx.y >> 3;
  const int oc0 = (blockIdx.y & 7) * 32;
  const int p = blockIdx.x * 256 + threadIdx.x;
  if (p >= HW) return;
  const int b = zi >> 1, head = zi & 1;
  const float* bias = head ? mv1_b : hm1_b;
  float* outp = (head ? MVR : HMR) + (size_t)b * 256 * HW;
  for (int oc = oc0; oc < oc0 + 32; oc++) {
    float s = bias[oc];
    #pragma unroll
    for (int sp = 0; sp < 3; sp++)
      s += part[((size_t)(sp * 4 + zi) * 256 + oc) * 1344 + p];
    outp[(size_t)oc * HW + p] = s > 0.f ? s : 0.f;
  }
}

// ---------------- thin 1x1 heads ----------------
template<int MOUT, int MP, int EP>
__global__ __launch_bounds__(64) void head_k(const float* __restrict__ in,
                                             const float* __restrict__ w,
                                             const float* __restrict__ bias,
                                             float* __restrict__ out) {
  __shared__ float wl[256 * MP];
  const int f = blockIdx.y;
  const int p = blockIdx.x * 64 + threadIdx.x;
  for (int idx = threadIdx.x; idx < 256 * MP; idx += 64) {
    const int c = idx / MP, mm = idx % MP;
    wl[idx] = (mm < MOUT) ? w[mm * 256 + c] : 0.f;
  }
  __syncthreads();
  if (p >= HW) return;
  float acc[MP] = {};
  const float* ib = in + (size_t)f * 256 * HW + p;
  for (int c = 0; c < 256; c++) {
    const float v = ib[(size_t)c * HW];
    #pragma unroll
    for (int j = 0; j < MP; j++) acc[j] = fmaf(wl[c * MP + j], v, acc[j]);
  }
  if constexpr (EP == 0) {
    #pragma unroll
    for (int mm = 0; mm < MOUT; mm++) {
      const float v = acc[mm] + bias[mm];
      out[(size_t)(f * 24 + mm) * HW + p] = 1.f / (1.f + __expf(-v));
    }
  } else if constexpr (EP == 1) {
    #pragma unroll
    for (int mm = 0; mm < MOUT; mm++)
      out[62208 + (size_t)(f * 14 + mm) * HW + p] = acc[mm] + bias[mm];
  } else {
    const int bb = f / 7, kk = f % 7;
    #pragma unroll
    for (int mm = 0; mm < MOUT; mm++)
      out[98496 + (size_t)(bb * 14 + kk * 2 + mm) * HW + p] = acc[mm] + bias[mm];
  }
}

// ---------- workspace layout (bytes); liveness as in round 5 (validated) ----------
constexpr size_t OFF_Q    = 0;
constexpr size_t OFF_K    = 4653056;
constexpr size_t OFF_V    = 9306112;
constexpr size_t OFF_Y    = 13959168;
constexpr size_t OFF_Z    = 23248896;
constexpr size_t OFF_YP   = 23248896;
constexpr size_t OFF_ML   = 60473344;
constexpr size_t OFF_PART = 0;
constexpr size_t OFF_WHR  = 16515328;
constexpr size_t OFF_HMR  = 35094784;
constexpr size_t OFF_MVR  = 37748992;
constexpr size_t OFF_SP   = 41828352;
constexpr size_t OFF_WWH  = 61054976;
constexpr size_t OFF_WHM  = 61349888;
constexpr size_t OFF_WMV  = 63414272;

}  // namespace

extern "C" void kernel_launch(void* const* d_in, const int* in_sizes, int n_in,
                              void* d_out, int out_size, void* d_ws, size_t ws_size,
                              hipStream_t stream) {
  const float* x     = (const float*)d_in[0];
  const float* g_w   = (const float*)d_in[1];
  const float* g_b   = (const float*)d_in[2];
  const float* th_w  = (const float*)d_in[3];
  const float* th_b  = (const float*)d_in[4];
  const float* ph_w  = (const float*)d_in[5];
  const float* ph_b  = (const float*)d_in[6];
  const float* wz_w  = (const float*)d_in[7];
  const float* wz_b  = (const float*)d_in[8];
  const float* wz_g  = (const float*)d_in[9];
  const float* wz_be = (const float*)d_in[10];
  const float* wz_m  = (const float*)d_in[11];
  const float* wz_v  = (const float*)d_in[12];
  const float* sh_w  = (const float*)d_in[13];
  const float* sh_g  = (const float*)d_in[14];
  const float* sh_be = (const float*)d_in[15];
  const float* sh_m  = (const float*)d_in[16];
  const float* sh_v  = (const float*)d_in[17];
  const float* wh1_w = (const float*)d_in[18];
  const float* wh1_b = (const float*)d_in[19];
  const float* wh2_w = (const float*)d_in[20];
  const float* wh2_b = (const float*)d_in[21];
  const float* hm1_w = (const float*)d_in[22];
  const float* hm1_b = (const float*)d_in[23];
  const float* hmc_w = (const float*)d_in[24];
  const float* hmc_b = (const float*)d_in[25];
  const float* mv1_w = (const float*)d_in[26];
  const float* mv1_b = (const float*)d_in[27];
  const float* mv2_w = (const float*)d_in[28];
  const float* mv2_b = (const float*)d_in[29];
  float* out = (float*)d_out;
  char* ws = (char*)d_ws;

  _Float16* Q   = (_Float16*)(ws + OFF_Q);
  _Float16* Kb  = (_Float16*)(ws + OFF_K);
  _Float16* Vt  = (_Float16*)(ws + OFF_V);
  float*    Y   = (float*)(ws + OFF_Y);
  float*    Z   = (float*)(ws + OFF_Z);
  float*    YP  = (float*)(ws + OFF_YP);
  float*    ML  = (float*)(ws + OFF_ML);
  float*    PART= (float*)(ws + OFF_PART);
  float*    WHR = (float*)(ws + OFF_WHR);
  float*    HMR = (float*)(ws + OFF_HMR);
  float*    MVR = (float*)(ws + OFF_MVR);
  _Float16* Sp  = (_Float16*)(ws + OFF_SP);
  _Float16* Wwh = (_Float16*)(ws + OFF_WWH);
  _Float16* Whm = (_Float16*)(ws + OFF_WHM);
  _Float16* Wmv = (_Float16*)(ws + OFF_WMV);

  // 0. repack conv weights -> f16 k-blocked
  repack_w<<<dim3(126, 32, 3), 256, 0, stream>>>(wh1_w, hm1_w, mv1_w, Wwh, Whm, Wmv);
  // 1. fused theta/phi/g projections
  {
    ProjOp op{th_w, ph_w, g_w, th_b, ph_b, g_b, x, Q, Kb, Vt};
    gemm_t<256, 128, ProjOp><<<dim3(71, 6, 2), 256, 0, stream>>>(op);
  }
  // 2. flash attention (r5 structure + XOR swizzle) + z-split combine -> Y
  attn_k<<<dim3(142 * 8), 256, 0, stream>>>(Q, Kb, Vt, YP, ML);
  attn_combine<<<dim3(36, 2, 8), 256, 0, stream>>>(YP, ML, Y);
  // 3. zero padded-S (after YP dead), then Wz + BN + residual -> Z
  hipMemsetAsync(Sp, 0, (size_t)14 * PADP * 64 * 2, stream);
  {
    WzOp op{wz_w, wz_b, wz_g, wz_be, wz_m, wz_v, x, Y, Z};
    gemm_t<128, 128, WzOp><<<dim3(71, 4, 2), 256, 0, stream>>>(op);
  }
  // 4. shrink + BN -> padded f16 S
  {
    ShOp op{sh_w, sh_g, sh_be, sh_m, sh_v, Z, Sp};
    gemm_t<256, 64, ShOp><<<dim3(142, 1, 2), 256, 0, stream>>>(op);
  }
  // 5. wh 3x3 conv (MFMA) + bias + relu -> WHR
  conv_wh_mfma<<<dim3(21, 2, 14), 256, 0, stream>>>(Sp, Wwh, wh1_b, WHR);
  // 6. hm & mv 3x3 convs (MFMA, k-split x3) -> partials, then combine
  conv_hm_mfma<<<dim3(21, 2, 12), 256, 0, stream>>>(Sp, Whm, Wmv, PART);
  conv_combine<<<dim3(6, 32), 256, 0, stream>>>(PART, hm1_b, mv1_b, HMR, MVR);
  // 7. heads
  head_k<24, 24, 0><<<dim3(21, 2), 64, 0, stream>>>(HMR, hmc_w, hmc_b, out);
  head_k<14, 16, 1><<<dim3(21, 2), 64, 0, stream>>>(MVR, mv2_w, mv2_b, out);
  head_k<2, 2, 2><<<dim3(21, 14), 64, 0, stream>>>(WHR, wh2_w, wh2_b, out);
}